// Round 11
// baseline (5340.109 us; speedup 1.0000x reference)
//
#include <hip/hip_runtime.h>

typedef _Float16 f16;
typedef _Float16 h2 __attribute__((ext_vector_type(2)));
typedef _Float16 h8 __attribute__((ext_vector_type(8)));
typedef float f4 __attribute__((ext_vector_type(4)));

constexpr int Bb = 64, Tt = 2048, Xx = 128, Hh = 256, G4 = 1024, Z2 = 128;

__device__ __forceinline__ float fdot2f(h2 a, h2 b, float c) {
#if __has_builtin(__builtin_amdgcn_fdot2)
  return __builtin_amdgcn_fdot2(a, b, c, false);
#else
  return c + (float)a[0] * (float)b[0] + (float)a[1] * (float)b[1];
#endif
}
__device__ __forceinline__ float tanhf_(float x) {
  float e = __expf(2.0f * x);
  return 1.0f - 2.0f * __builtin_amdgcn_rcpf(e + 1.0f);
}
__device__ __forceinline__ h2 bch2(unsigned int u) { return __builtin_bit_cast(h2, u); }

template <int CTRL>
__device__ __forceinline__ float qb(float v) {  // quad_perm shuffle
  return __builtin_bit_cast(float,
      __builtin_amdgcn_mov_dpp(__builtin_bit_cast(int, v), CTRL, 0xf, 0xf, true));
}

// ---------------- casts ----------------
__global__ void cast_f16_k(const float* __restrict__ in, f16* __restrict__ out, int n) {
  int i = (blockIdx.x * 256 + threadIdx.x) * 4;
  if (i >= n) return;
  float4 v = *(const float4*)(in + i);
  h2 a = {(f16)v.x, (f16)v.y};
  h2 b = {(f16)v.z, (f16)v.w};
  uint2 o = {__builtin_bit_cast(unsigned int, a), __builtin_bit_cast(unsigned int, b)};
  *(uint2*)(out + i) = o;
}

// Wi columns permuted to quad-gate order col' = 4j+g  (orig col = g*256+j):
// xp then has the 4 gate pre-activations of unit j contiguous -> one uint2 load.
__global__ void cast_wiP_k(const float* __restrict__ Wi, f16* __restrict__ out) {
  int idx = blockIdx.x * 256 + threadIdx.x;  // 131072 = 128*1024
  int k = idx >> 10, cp = idx & 1023;
  out[idx] = (f16)Wi[(long)k * G4 + (cp & 3) * 256 + (cp >> 2)];
}
__global__ void cast_bhp_k(const float* __restrict__ bh, float* __restrict__ bhp) {
  int cp = blockIdx.x * 256 + threadIdx.x;   // 1024
  bhp[cp] = bh[(cp & 3) * 256 + (cp >> 2)];
}

// v512h-layout (LDS-tail kernel): thread pair (2j,2j+1) owns unit j; lane half
// hf covers K in [128hf,128hf+128) for ALL 4 gates. Slot s = 16i+4g+m ->
// k = 128hf + 8i + 2m (+e). i<12 -> registers (192 h2); i in [12,16) -> LDS.
__global__ void cast_whT4_k(const float* __restrict__ Wh, f16* __restrict__ WhT4) {
  int idx = blockIdx.x * 256 + threadIdx.x;  // 262144 = 512 threads * 512 f16
  int tid = idx >> 9, f = idx & 511;
  int s = f >> 1, e = f & 1;
  int i = s >> 4, g = (s >> 2) & 3, m = s & 3;
  int j = tid >> 1, hf = tid & 1;
  int k = 128 * hf + 8 * i + 2 * m + e;
  WhT4[(long)tid * 512 + f] = (f16)Wh[(long)k * G4 + g * 256 + j];
}

// v512s-layout (streamed-tail kernel): head i<10 -> 160 reg h2 per thread
// (Wh5h[tid*320 + f]); tail i in [10,16) -> global array wtail, one uint4 per
// (group i' = (i-10)*4+g, tid), coalesced: f16 addr = (i'*512+tid)*8 + 2m+e.
__global__ void cast_whT5_k(const float* __restrict__ Wh,
                            f16* __restrict__ Wh5h, f16* __restrict__ wtail) {
  int idx = blockIdx.x * 256 + threadIdx.x;  // 262144 total
  if (idx < 512 * 320) {
    int tid = idx / 320, f = idx % 320;
    int s = f >> 1, e = f & 1;
    int i = s >> 4, g = (s >> 2) & 3, m = s & 3;
    int j = tid >> 1, hf = tid & 1;
    int k = 128 * hf + 8 * i + 2 * m + e;
    Wh5h[idx] = (f16)Wh[(long)k * G4 + g * 256 + j];
  } else {
    int r = idx - 512 * 320;                 // < 98304
    int u4 = r >> 3, me = r & 7;
    int m = me >> 1, e = me & 1;
    int ip = u4 >> 9, tid = u4 & 511;        // ip in [0,24)
    int i = 10 + (ip >> 2), g = ip & 3;
    int j = tid >> 1, hf = tid & 1;
    int k = 128 * hf + 8 * i + 2 * m + e;
    wtail[r] = (f16)Wh[(long)k * G4 + g * 256 + j];
  }
}

// ---------------- generic f16 MFMA GEMM, 64x64 tile ----------------
__global__ __launch_bounds__(256, 4) void gemm_f16_k(
    const f16* __restrict__ A, const f16* __restrict__ Bm, const float* __restrict__ bias,
    f16* __restrict__ C16, float* __restrict__ Cmu, float* __restrict__ Cls,
    int N, int K, int a_shift, int a_ostride, int a_t0,
    int mode, int o_t0, int tcshift)
{
  __shared__ __align__(16) f16 At[64][48];
  __shared__ __align__(16) f16 Bt[64][48];
  const int tid = threadIdx.x;
  const int mblk = blockIdx.x, nblk = blockIdx.y;
  const int w = tid >> 6, lane = tid & 63;

  const int sa_row = tid >> 2, sa_k = (tid & 3) * 8;
  const int m_g = mblk * 64 + sa_row;
  const long arow = (long)(m_g >> a_shift) * a_ostride + a_t0 + (m_g & ((1 << a_shift) - 1));
  const f16* aptr = A + arow * K + sa_k;
  const int sb_k = tid >> 3, sb_n = (tid & 7) * 8;
  const f16* bptr = Bm + (long)sb_k * N + nblk * 64 + sb_n;

  f4 acc[4];
#pragma unroll
  for (int i = 0; i < 4; ++i) acc[i] = (f4){0.f, 0.f, 0.f, 0.f};

  const int arow_l = w * 16 + (lane & 15);
  const int k0 = (lane >> 4) * 8;

  for (int kk = 0; kk < K; kk += 32) {
    uint4 av = *(const uint4*)(aptr + kk);
    uint4 bv = *(const uint4*)(bptr + (long)kk * N);
    __syncthreads();
    *(uint4*)&At[sa_row][sa_k] = av;
    h8 bx = __builtin_bit_cast(h8, bv);
#pragma unroll
    for (int j = 0; j < 8; ++j) Bt[sb_n + j][sb_k] = bx[j];
    __syncthreads();
    h8 af = *(const h8*)&At[arow_l][k0];
#pragma unroll
    for (int nt = 0; nt < 4; ++nt) {
      h8 bf = *(const h8*)&Bt[nt * 16 + (lane & 15)][k0];
      acc[nt] = __builtin_amdgcn_mfma_f32_16x16x32_f16(af, bf, acc[nt], 0, 0, 0);
    }
  }

  const int row_l = w * 16 + ((lane >> 4) << 2);
  const int col_l = lane & 15;
#pragma unroll
  for (int nt = 0; nt < 4; ++nt) {
    int gcol = nblk * 64 + nt * 16 + col_l;
    float bv = bias[gcol];
#pragma unroll
    for (int r = 0; r < 4; ++r) {
      int gm = mblk * 64 + row_l + r;
      float val = acc[nt][r] + bv;
      if (mode == 1) val = fmaxf(val, 0.f);
      if (mode <= 1) {
        C16[(long)gm * N + gcol] = (f16)val;
      } else {
        int bb = gm >> tcshift, tl = gm & ((1 << tcshift) - 1);
        long orow = (long)bb * Tt + o_t0 + tl;
        if (gcol < 64) Cmu[orow * 64 + gcol] = val;
        else Cls[orow * 64 + (gcol - 64)] = val;
      }
    }
  }
}

// hbuf pad layout (both scans): h K-half0 = f16 slots [0,128) at bytes [0,256),
// half1 at bytes [272,528) (16B pad). Odd-lane dwords hit banks 4i+4..4i+7 vs
// even 4i..4i+3 -> disjoint, kills r10's 3.35e7 two-address conflicts.
// f16 slot for unit j: j + ((j>>7)<<3). h2 slot for h_state word tid: tid + ((tid>>6)<<2).

// ---------------- v512s scan: streamed L2 weight tail (chunk 0) -------------
// 160 reg h2 + 96 h2 streamed from L2 per step (loop-invariant, coalesced,
// 192 KB total -> L2-resident). LDS traffic/step drops to 16 padded h-reads.
__global__ void __launch_bounds__(512, 2) lstm512s_k(
    const f16* __restrict__ Wh5h, const f16* __restrict__ wtail,
    const f16* __restrict__ xp, f16* __restrict__ hout,
    float* __restrict__ c_state, f16* __restrict__ h_state, int TC, int first)
{
  const int b = blockIdx.x, tid = threadIdx.x;
  const int j = tid >> 1, hf = tid & 1;
  __shared__ __align__(16) h2 hbuf[2][136];

  h2 w[160];
  {
    const uint4* p4 = (const uint4*)(Wh5h + (long)tid * 320);
#pragma unroll
    for (int u = 0; u < 40; ++u) {
      uint4 v = p4[u];
      w[4 * u + 0] = bch2(v.x); w[4 * u + 1] = bch2(v.y);
      w[4 * u + 2] = bch2(v.z); w[4 * u + 3] = bch2(v.w);
    }
  }
  const uint4* tp = (const uint4*)wtail + tid;

  float c = first ? 0.f : c_state[b * Hh + j];
  if (tid < 128) {
    h2 hz = {(f16)0.f, (f16)0.f};
    hbuf[0][tid + ((tid >> 6) << 2)] =
        first ? hz : ((const h2*)h_state)[b * 128 + tid];
  }
  __syncthreads();

  const f16* xptr = xp + (long)b * TC * G4 + 4 * j;
  const f16* xend = xptr + (long)(TC - 1) * G4;
  uint2 xv = *(const uint2*)xptr;
  int p = 0;
  for (int t = 0; t < TC; ++t) {
    const f16* xnp = (xptr == xend) ? xptr : xptr + G4;
    uint2 xn = *(const uint2*)xnp;

    uint4 A0 = tp[0], A1 = tp[512], A2 = tp[1024], A3 = tp[1536];
    uint4 B0 = tp[2048], B1 = tp[2560], B2 = tp[3072], B3 = tp[3584];

    const uint4* hq = (const uint4*)&hbuf[p][0] + hf * 17;
    float d0 = 0.f, d1 = 0.f, d2 = 0.f, d3 = 0.f;
#pragma unroll
    for (int i = 0; i < 10; ++i) {
      uint4 hv = hq[i];
      h2 h0 = bch2(hv.x), h1 = bch2(hv.y), h2_ = bch2(hv.z), h3 = bch2(hv.w);
      d0 = fdot2f(w[16 * i + 0], h0, d0);   d0 = fdot2f(w[16 * i + 1], h1, d0);
      d0 = fdot2f(w[16 * i + 2], h2_, d0);  d0 = fdot2f(w[16 * i + 3], h3, d0);
      d1 = fdot2f(w[16 * i + 4], h0, d1);   d1 = fdot2f(w[16 * i + 5], h1, d1);
      d1 = fdot2f(w[16 * i + 6], h2_, d1);  d1 = fdot2f(w[16 * i + 7], h3, d1);
      d2 = fdot2f(w[16 * i + 8], h0, d2);   d2 = fdot2f(w[16 * i + 9], h1, d2);
      d2 = fdot2f(w[16 * i + 10], h2_, d2); d2 = fdot2f(w[16 * i + 11], h3, d2);
      d3 = fdot2f(w[16 * i + 12], h0, d3);  d3 = fdot2f(w[16 * i + 13], h1, d3);
      d3 = fdot2f(w[16 * i + 14], h2_, d3); d3 = fdot2f(w[16 * i + 15], h3, d3);
    }
#pragma unroll
    for (int ii = 0; ii < 6; ++ii) {
      uint4 C0 = {0, 0, 0, 0}, C1 = C0, C2 = C0, C3 = C0;
      if (ii < 4) {
        const uint4* np = tp + (size_t)(4 * (ii + 2)) * 512;
        C0 = np[0]; C1 = np[512]; C2 = np[1024]; C3 = np[1536];
      }
      uint4 hv = hq[10 + ii];
      h2 h0 = bch2(hv.x), h1 = bch2(hv.y), h2_ = bch2(hv.z), h3 = bch2(hv.w);
      d0 = fdot2f(bch2(A0.x), h0, d0); d0 = fdot2f(bch2(A0.y), h1, d0);
      d0 = fdot2f(bch2(A0.z), h2_, d0); d0 = fdot2f(bch2(A0.w), h3, d0);
      d1 = fdot2f(bch2(A1.x), h0, d1); d1 = fdot2f(bch2(A1.y), h1, d1);
      d1 = fdot2f(bch2(A1.z), h2_, d1); d1 = fdot2f(bch2(A1.w), h3, d1);
      d2 = fdot2f(bch2(A2.x), h0, d2); d2 = fdot2f(bch2(A2.y), h1, d2);
      d2 = fdot2f(bch2(A2.z), h2_, d2); d2 = fdot2f(bch2(A2.w), h3, d2);
      d3 = fdot2f(bch2(A3.x), h0, d3); d3 = fdot2f(bch2(A3.y), h1, d3);
      d3 = fdot2f(bch2(A3.z), h2_, d3); d3 = fdot2f(bch2(A3.w), h3, d3);
      A0 = B0; A1 = B1; A2 = B2; A3 = B3;
      B0 = C0; B1 = C1; B2 = C2; B3 = C3;
    }

    d0 += qb<0xB1>(d0); d1 += qb<0xB1>(d1);
    d2 += qb<0xB1>(d2); d3 += qb<0xB1>(d3);

    h2 xlo = bch2(xv.x), xhi = bch2(xv.y);
    float ti = d0 + (float)xlo[0], tf = d1 + (float)xlo[1];
    float tg = d2 + (float)xhi[0], to = d3 + (float)xhi[1];
    float ai = __builtin_amdgcn_rcpf(1.0f + __expf(-ti));
    float af = __builtin_amdgcn_rcpf(1.0f + __expf(-tf));
    float ag = 1.0f - 2.0f * __builtin_amdgcn_rcpf(1.0f + __expf(2.0f * tg));
    float ao = __builtin_amdgcn_rcpf(1.0f + __expf(-to));
    c = af * c + ai * ag;
    float hval = ao * tanhf_(c);
    if (!hf) {
      f16 hh = (f16)hval;
      ((f16*)&hbuf[p ^ 1][0])[j + ((j >> 7) << 3)] = hh;
      hout[((long)b * TC + t) * Hh + j] = hh;
    }
    __syncthreads();
    p ^= 1;
    xv = xn;
    xptr = xnp;
  }
  if (!hf) c_state[b * Hh + j] = c;
  if (tid < 128)
    ((h2*)h_state)[b * 128 + tid] = hbuf[p][tid + ((tid >> 6) << 2)];
}

// ---------------- v512hf scan: LDS tail, pad + uint2-xp fixes (chunk 1) -----
__global__ void __launch_bounds__(512, 2) lstm512hf_k(
    const f16* __restrict__ WhT4, const f16* __restrict__ xp,
    f16* __restrict__ hout, float* __restrict__ c_state, f16* __restrict__ h_state,
    int TC, int first)
{
  const int b = blockIdx.x, tid = threadIdx.x;
  const int j = tid >> 1, hf = tid & 1;
  __shared__ __align__(16) h2 hbuf[2][136];
  __shared__ uint4 wt[16][512];               // weight tail (i in [12,16)): 128 KB

  h2 w[192];
  {
    const uint4* p4 = (const uint4*)(WhT4 + (long)tid * 512);
#pragma unroll
    for (int u = 0; u < 48; ++u) {
      uint4 v = p4[u];
      w[4 * u + 0] = bch2(v.x); w[4 * u + 1] = bch2(v.y);
      w[4 * u + 2] = bch2(v.z); w[4 * u + 3] = bch2(v.w);
    }
#pragma unroll
    for (int gg = 0; gg < 16; ++gg) wt[gg][tid] = p4[48 + gg];
  }

  float c = first ? 0.f : c_state[b * Hh + j];
  if (tid < 128) {
    h2 hz = {(f16)0.f, (f16)0.f};
    hbuf[0][tid + ((tid >> 6) << 2)] =
        first ? hz : ((const h2*)h_state)[b * 128 + tid];
  }
  __syncthreads();

  const f16* xptr = xp + (long)b * TC * G4 + 4 * j;
  const f16* xend = xptr + (long)(TC - 1) * G4;
  uint2 xv = *(const uint2*)xptr;
  int p = 0;
  for (int t = 0; t < TC; ++t) {
    const f16* xnp = (xptr == xend) ? xptr : xptr + G4;
    uint2 xn = *(const uint2*)xnp;

    float d0 = 0.f, d1 = 0.f, d2 = 0.f, d3 = 0.f;
    const uint4* hq = (const uint4*)&hbuf[p][0] + hf * 17;
#pragma unroll
    for (int i = 0; i < 12; ++i) {
      uint4 hv = hq[i];
      h2 h0 = bch2(hv.x), h1 = bch2(hv.y), h2_ = bch2(hv.z), h3 = bch2(hv.w);
      d0 = fdot2f(w[16 * i + 0], h0, d0);   d0 = fdot2f(w[16 * i + 1], h1, d0);
      d0 = fdot2f(w[16 * i + 2], h2_, d0);  d0 = fdot2f(w[16 * i + 3], h3, d0);
      d1 = fdot2f(w[16 * i + 4], h0, d1);   d1 = fdot2f(w[16 * i + 5], h1, d1);
      d1 = fdot2f(w[16 * i + 6], h2_, d1);  d1 = fdot2f(w[16 * i + 7], h3, d1);
      d2 = fdot2f(w[16 * i + 8], h0, d2);   d2 = fdot2f(w[16 * i + 9], h1, d2);
      d2 = fdot2f(w[16 * i + 10], h2_, d2); d2 = fdot2f(w[16 * i + 11], h3, d2);
      d3 = fdot2f(w[16 * i + 12], h0, d3);  d3 = fdot2f(w[16 * i + 13], h1, d3);
      d3 = fdot2f(w[16 * i + 14], h2_, d3); d3 = fdot2f(w[16 * i + 15], h3, d3);
    }
#pragma unroll
    for (int i = 12; i < 16; ++i) {
      uint4 hv = hq[i];
      h2 h0 = bch2(hv.x), h1 = bch2(hv.y), h2_ = bch2(hv.z), h3 = bch2(hv.w);
      uint4 w0 = wt[(i - 12) * 4 + 0][tid];
      uint4 w1 = wt[(i - 12) * 4 + 1][tid];
      uint4 w2 = wt[(i - 12) * 4 + 2][tid];
      uint4 w3 = wt[(i - 12) * 4 + 3][tid];
      d0 = fdot2f(bch2(w0.x), h0, d0); d0 = fdot2f(bch2(w0.y), h1, d0);
      d0 = fdot2f(bch2(w0.z), h2_, d0); d0 = fdot2f(bch2(w0.w), h3, d0);
      d1 = fdot2f(bch2(w1.x), h0, d1); d1 = fdot2f(bch2(w1.y), h1, d1);
      d1 = fdot2f(bch2(w1.z), h2_, d1); d1 = fdot2f(bch2(w1.w), h3, d1);
      d2 = fdot2f(bch2(w2.x), h0, d2); d2 = fdot2f(bch2(w2.y), h1, d2);
      d2 = fdot2f(bch2(w2.z), h2_, d2); d2 = fdot2f(bch2(w2.w), h3, d2);
      d3 = fdot2f(bch2(w3.x), h0, d3); d3 = fdot2f(bch2(w3.y), h1, d3);
      d3 = fdot2f(bch2(w3.z), h2_, d3); d3 = fdot2f(bch2(w3.w), h3, d3);
    }

    d0 += qb<0xB1>(d0); d1 += qb<0xB1>(d1);
    d2 += qb<0xB1>(d2); d3 += qb<0xB1>(d3);

    h2 xlo = bch2(xv.x), xhi = bch2(xv.y);
    float ti = d0 + (float)xlo[0], tf = d1 + (float)xlo[1];
    float tg = d2 + (float)xhi[0], to = d3 + (float)xhi[1];
    float ai = __builtin_amdgcn_rcpf(1.0f + __expf(-ti));
    float af = __builtin_amdgcn_rcpf(1.0f + __expf(-tf));
    float ag = 1.0f - 2.0f * __builtin_amdgcn_rcpf(1.0f + __expf(2.0f * tg));
    float ao = __builtin_amdgcn_rcpf(1.0f + __expf(-to));
    c = af * c + ai * ag;
    float hval = ao * tanhf_(c);
    if (!hf) {
      f16 hh = (f16)hval;
      ((f16*)&hbuf[p ^ 1][0])[j + ((j >> 7) << 3)] = hh;
      hout[((long)b * TC + t) * Hh + j] = hh;
    }
    __syncthreads();
    p ^= 1;
    xv = xn;
    xptr = xnp;
  }
  if (!hf) c_state[b * Hh + j] = c;
  if (tid < 128)
    ((h2*)h_state)[b * 128 + tid] = hbuf[p][tid + ((tid >> 6) << 2)];
}

// ---------------- host ----------------
extern "C" void kernel_launch(void* const* d_in, const int* in_sizes, int n_in,
                              void* d_out, int out_size, void* d_ws, size_t ws_size,
                              hipStream_t stream)
{
  const float* x  = (const float*)d_in[0];
  const float* Wi = (const float*)d_in[1];
  const float* Wh = (const float*)d_in[2];
  const float* bh = (const float*)d_in[3];
  const float* W1 = (const float*)d_in[4];
  const float* b1 = (const float*)d_in[5];
  const float* W2 = (const float*)d_in[6];
  const float* b2 = (const float*)d_in[7];
  float* out = (float*)d_out;

  char* ws = (char*)d_ws;
  size_t off = 0;
  auto alloc = [&](size_t bytes) -> char* {
    char* p = ws + off;
    off = (off + bytes + 255) & ~(size_t)255;
    return p;
  };
  f16* x16    = (f16*)alloc((size_t)Bb * Tt * Xx * 2);
  f16* wi16p  = (f16*)alloc((size_t)Xx * G4 * 2);
  float* bhp  = (float*)alloc((size_t)G4 * 4);
  f16* whT4   = (f16*)alloc((size_t)G4 * Hh * 2);
  f16* wh5h   = (f16*)alloc((size_t)512 * 320 * 2);
  f16* wtail  = (f16*)alloc((size_t)24 * 512 * 8 * 2);
  f16* w116   = (f16*)alloc((size_t)Hh * Hh * 2);
  f16* w216   = (f16*)alloc((size_t)Hh * Z2 * 2);
  float* cst  = (float*)alloc((size_t)Bb * Hh * 4);
  f16* hst    = (f16*)alloc((size_t)Bb * Hh * 2);

  int tc = 1024;  // 2 chunks: chunk0 = streamed-tail, chunk1 = LDS-tail
  while (tc > 32) {
    size_t need = (size_t)Bb * tc * G4 * 2 + (size_t)Bb * tc * Hh * 2;
    if (off + need <= ws_size) break;
    tc >>= 1;
  }
  int tcsh = __builtin_ctz((unsigned)tc);
  f16* xp16 = (f16*)alloc((size_t)Bb * tc * G4 * 2);
  f16* h16  = (f16*)alloc((size_t)Bb * tc * Hh * 2);
  f16* hid16 = xp16;  // head hidden aliases xp (xp fully consumed by the scan)

  cast_f16_k<<<(Bb * Tt * Xx) / 1024, 256, 0, stream>>>(x, x16, Bb * Tt * Xx);
  cast_wiP_k<<<(Xx * G4) / 256, 256, 0, stream>>>(Wi, wi16p);
  cast_bhp_k<<<4, 256, 0, stream>>>(bh, bhp);
  cast_f16_k<<<(Hh * Hh) / 1024, 256, 0, stream>>>(W1, w116, Hh * Hh);
  cast_f16_k<<<(Hh * Z2) / 1024, 256, 0, stream>>>(W2, w216, Hh * Z2);
  cast_whT4_k<<<(Hh * G4) / 256, 256, 0, stream>>>(Wh, whT4);
  cast_whT5_k<<<(Hh * G4) / 256, 256, 0, stream>>>(Wh, wh5h, wtail);

  float* mu = out;
  float* ls = out + (size_t)Bb * Tt * 64;

  int ci = 0;
  for (int t0 = 0; t0 < Tt; t0 += tc, ++ci) {
    dim3 gx(Bb * tc / 64, G4 / 64);
    gemm_f16_k<<<gx, 256, 0, stream>>>(x16, wi16p, bhp, xp16, nullptr, nullptr,
                                       G4, Xx, tcsh, Tt, t0, 0, 0, 0);
    if (ci == 0)
      lstm512s_k<<<Bb, 512, 0, stream>>>(wh5h, wtail, xp16, h16, cst, hst, tc,
                                         (t0 == 0) ? 1 : 0);
    else
      lstm512hf_k<<<Bb, 512, 0, stream>>>(whT4, xp16, h16, cst, hst, tc,
                                          (t0 == 0) ? 1 : 0);
    dim3 g1g(Bb * tc / 64, Hh / 64);
    gemm_f16_k<<<g1g, 256, 0, stream>>>(h16, w116, b1, hid16, nullptr, nullptr,
                                        Hh, Hh, 30, 0, 0, 1, 0, 0);
    dim3 g2g(Bb * tc / 64, Z2 / 64);
    gemm_f16_k<<<g2g, 256, 0, stream>>>(hid16, w216, b2, nullptr, mu, ls,
                                        Z2, Hh, 30, 0, 0, 2, t0, tcsh);
  }
}

// Round 12
// 3287.988 us; speedup vs baseline: 1.6241x; 1.6241x over previous
//
#include <hip/hip_runtime.h>

typedef _Float16 f16;
typedef _Float16 h2 __attribute__((ext_vector_type(2)));
typedef _Float16 h8 __attribute__((ext_vector_type(8)));
typedef float f4 __attribute__((ext_vector_type(4)));

constexpr int Bb = 64, Tt = 2048, Xx = 128, Hh = 256, G4 = 1024, Z2 = 128;

__device__ __forceinline__ float fdot2f(h2 a, h2 b, float c) {
#if __has_builtin(__builtin_amdgcn_fdot2)
  return __builtin_amdgcn_fdot2(a, b, c, false);
#else
  return c + (float)a[0] * (float)b[0] + (float)a[1] * (float)b[1];
#endif
}
// forced v_pk_fma_f16 (2 f16 FMAs/instr, basic packed-ALU class -> full rate)
__device__ __forceinline__ h2 pkfma(h2 a, h2 b, h2 c) {
  h2 d;
  asm("v_pk_fma_f16 %0, %1, %2, %3" : "=v"(d) : "v"(a), "v"(b), "v"(c));
  return d;
}
__device__ __forceinline__ float tanhf_(float x) {
  float e = __expf(2.0f * x);
  return 1.0f - 2.0f * __builtin_amdgcn_rcpf(e + 1.0f);
}
__device__ __forceinline__ h2 bch2(unsigned int u) { return __builtin_bit_cast(h2, u); }

template <int CTRL>
__device__ __forceinline__ float qb(float v) {  // quad_perm shuffle
  return __builtin_bit_cast(float,
      __builtin_amdgcn_mov_dpp(__builtin_bit_cast(int, v), CTRL, 0xf, 0xf, true));
}

// ---------------- casts ----------------
__global__ void cast_f16_k(const float* __restrict__ in, f16* __restrict__ out, int n) {
  int i = (blockIdx.x * 256 + threadIdx.x) * 4;
  if (i >= n) return;
  float4 v = *(const float4*)(in + i);
  h2 a = {(f16)v.x, (f16)v.y};
  h2 b = {(f16)v.z, (f16)v.w};
  uint2 o = {__builtin_bit_cast(unsigned int, a), __builtin_bit_cast(unsigned int, b)};
  *(uint2*)(out + i) = o;
}

// v512-layout: thread tid owns packed cols c0=2tid, c1=2tid+1 (cc -> gate cc&3,
// unit cc>>2; thread's gates: even tid (i,f) of unit tid>>1, odd tid (g,o)).
__global__ void cast_whT2_k(const float* __restrict__ Wh, f16* __restrict__ WhT2) {
  int idx = blockIdx.x * 256 + threadIdx.x;  // 262144 = 512 threads * 512 f16
  int tid = idx >> 9, f = idx & 511;
  int s = f >> 1, e = f & 1;
  int c_off, k;
  if (s < 96)      { c_off = 0; k = 2 * s + e; }
  else if (s < 192){ c_off = 1; k = 2 * (s - 96) + e; }
  else if (s < 224){ c_off = 0; k = 192 + 2 * (s - 192) + e; }
  else             { c_off = 1; k = 192 + 2 * (s - 224) + e; }
  int cc = 2 * tid + c_off;
  int j = cc >> 2, g = cc & 3;
  WhT2[(long)tid * 512 + f] = (f16)Wh[(long)k * G4 + g * 256 + j];
}

// ---------------- generic f16 MFMA GEMM, 64x64 tile ----------------
__global__ __launch_bounds__(256, 4) void gemm_f16_k(
    const f16* __restrict__ A, const f16* __restrict__ Bm, const float* __restrict__ bias,
    f16* __restrict__ C16, float* __restrict__ Cmu, float* __restrict__ Cls,
    int N, int K, int a_shift, int a_ostride, int a_t0,
    int mode, int o_t0, int tcshift)
{
  __shared__ __align__(16) f16 At[64][48];
  __shared__ __align__(16) f16 Bt[64][48];
  const int tid = threadIdx.x;
  const int mblk = blockIdx.x, nblk = blockIdx.y;
  const int w = tid >> 6, lane = tid & 63;

  const int sa_row = tid >> 2, sa_k = (tid & 3) * 8;
  const int m_g = mblk * 64 + sa_row;
  const long arow = (long)(m_g >> a_shift) * a_ostride + a_t0 + (m_g & ((1 << a_shift) - 1));
  const f16* aptr = A + arow * K + sa_k;
  const int sb_k = tid >> 3, sb_n = (tid & 7) * 8;
  const f16* bptr = Bm + (long)sb_k * N + nblk * 64 + sb_n;

  f4 acc[4];
#pragma unroll
  for (int i = 0; i < 4; ++i) acc[i] = (f4){0.f, 0.f, 0.f, 0.f};

  const int arow_l = w * 16 + (lane & 15);
  const int k0 = (lane >> 4) * 8;

  for (int kk = 0; kk < K; kk += 32) {
    uint4 av = *(const uint4*)(aptr + kk);
    uint4 bv = *(const uint4*)(bptr + (long)kk * N);
    __syncthreads();
    *(uint4*)&At[sa_row][sa_k] = av;
    h8 bx = __builtin_bit_cast(h8, bv);
#pragma unroll
    for (int j = 0; j < 8; ++j) Bt[sb_n + j][sb_k] = bx[j];
    __syncthreads();
    h8 af = *(const h8*)&At[arow_l][k0];
#pragma unroll
    for (int nt = 0; nt < 4; ++nt) {
      h8 bf = *(const h8*)&Bt[nt * 16 + (lane & 15)][k0];
      acc[nt] = __builtin_amdgcn_mfma_f32_16x16x32_f16(af, bf, acc[nt], 0, 0, 0);
    }
  }

  const int row_l = w * 16 + ((lane >> 4) << 2);
  const int col_l = lane & 15;
#pragma unroll
  for (int nt = 0; nt < 4; ++nt) {
    int gcol = nblk * 64 + nt * 16 + col_l;
    float bv = bias[gcol];
#pragma unroll
    for (int r = 0; r < 4; ++r) {
      int gm = mblk * 64 + row_l + r;
      float val = acc[nt][r] + bv;
      if (mode == 1) val = fmaxf(val, 0.f);
      if (mode <= 1) {
        C16[(long)gm * N + gcol] = (f16)val;
      } else {
        int bb = gm >> tcshift, tl = gm & ((1 << tcshift) - 1);
        long orow = (long)bb * Tt + o_t0 + tl;
        if (gcol < 64) Cmu[orow * 64 + gcol] = val;
        else Cls[orow * 64 + (gcol - 64)] = val;
      }
    }
  }
}

// ---------------- v512p scan: pk_fma inner op (chunk 0, experiment) ---------
// Identical to lstm512_k except the 256 dot-MACs use v_pk_fma_f16 (full-rate
// packed ALU) with 8 independent f16x2 accumulator chains, combined in f32.
// Tests whether v_dot2_f32_f16 is a half-rate DOT-class op on CDNA4.
__global__ void __launch_bounds__(512, 2) lstm512p_k(
    const f16* __restrict__ WhT2, const f16* __restrict__ xp,
    f16* __restrict__ hout, float* __restrict__ c_state, f16* __restrict__ h_state,
    int TC, int first)
{
  const int b = blockIdx.x, tid = threadIdx.x;
  const int j = tid >> 1, odd = tid & 1;
  __shared__ __align__(16) h2 hbuf[2][128];
  __shared__ uint4 wt[16][512];

  h2 w[192];
  {
    const uint4* p4 = (const uint4*)(WhT2 + (long)tid * 512);
#pragma unroll
    for (int u = 0; u < 48; ++u) {
      uint4 v = p4[u];
      w[4 * u + 0] = bch2(v.x); w[4 * u + 1] = bch2(v.y);
      w[4 * u + 2] = bch2(v.z); w[4 * u + 3] = bch2(v.w);
    }
#pragma unroll
    for (int gg = 0; gg < 16; ++gg) wt[gg][tid] = p4[48 + gg];
  }

  float c = first ? 0.f : c_state[b * Hh + j];
  if (tid < 128) {
    h2 hz = {(f16)0.f, (f16)0.f};
    hbuf[0][tid] = first ? hz : ((const h2*)h_state)[b * 128 + tid];
  }
  __syncthreads();

  const float sgn0 = odd ? 2.0f : -1.0f;
  const int xcol0 = (odd * 2) * 256 + j;
  const int xcol1 = xcol0 + 256;
  const f16* xbase = xp + (long)b * TC * G4;
  const f16* xptr0 = xbase + xcol0;
  const f16* xptr1 = xbase + xcol1;
  const f16* xend0 = xptr0 + (long)(TC - 1) * G4;
  f16 xc0 = *xptr0, xc1 = *xptr1;
  int p = 0;
  const h2 hz2 = {(f16)0.f, (f16)0.f};
  for (int t = 0; t < TC; ++t) {
    bool last = (xptr0 == xend0);
    const f16* xn0p = last ? xptr0 : xptr0 + G4;
    const f16* xn1p = last ? xptr1 : xptr1 + G4;
    f16 xn0 = *xn0p, xn1 = *xn1p;

    h2 A0 = hz2, A1 = hz2, A2 = hz2, A3 = hz2;   // col0: 4 indep f16x2 chains
    h2 B0 = hz2, B1 = hz2, B2 = hz2, B3 = hz2;   // col1
    const uint4* hb4 = (const uint4*)&hbuf[p][0];
#pragma unroll
    for (int i = 0; i < 24; ++i) {
      uint4 hv = hb4[i];
      h2 h0 = bch2(hv.x), h1 = bch2(hv.y), h2_ = bch2(hv.z), h3 = bch2(hv.w);
      A0 = pkfma(w[4 * i + 0], h0, A0);
      A1 = pkfma(w[4 * i + 1], h1, A1);
      A2 = pkfma(w[4 * i + 2], h2_, A2);
      A3 = pkfma(w[4 * i + 3], h3, A3);
      B0 = pkfma(w[96 + 4 * i + 0], h0, B0);
      B1 = pkfma(w[96 + 4 * i + 1], h1, B1);
      B2 = pkfma(w[96 + 4 * i + 2], h2_, B2);
      B3 = pkfma(w[96 + 4 * i + 3], h3, B3);
    }
#pragma unroll
    for (int gg = 0; gg < 8; ++gg) {
      uint4 hv = hb4[24 + gg];
      uint4 wa = wt[gg][tid];
      uint4 wb = wt[8 + gg][tid];
      h2 h0 = bch2(hv.x), h1 = bch2(hv.y), h2_ = bch2(hv.z), h3 = bch2(hv.w);
      A0 = pkfma(bch2(wa.x), h0, A0);
      A1 = pkfma(bch2(wa.y), h1, A1);
      A2 = pkfma(bch2(wa.z), h2_, A2);
      A3 = pkfma(bch2(wa.w), h3, A3);
      B0 = pkfma(bch2(wb.x), h0, B0);
      B1 = pkfma(bch2(wb.y), h1, B1);
      B2 = pkfma(bch2(wb.z), h2_, B2);
      B3 = pkfma(bch2(wb.w), h3, B3);
    }
    h2 sA = (A0 + A1) + (A2 + A3);               // v_pk_add_f16 tree
    h2 sB = (B0 + B1) + (B2 + B3);
    float A0f = ((float)sA[0] + (float)sA[1]) + (float)xc0;
    float A1f = ((float)sB[0] + (float)sB[1]) + (float)xc1;

    float e0 = __expf(sgn0 * A0f);
    float r0 = __builtin_amdgcn_rcpf(1.0f + e0);
    float act0 = odd ? 1.0f - 2.0f * r0 : r0;
    float e1 = __expf(-A1f);
    float act1 = __builtin_amdgcn_rcpf(1.0f + e1);

    float px0 = qb<0xB1>(act0), px1 = qb<0xB1>(act1);
    float ai = odd ? px0 : act0;
    float af = odd ? px1 : act1;
    float ag = odd ? act0 : px0;
    float ao = odd ? act1 : px1;
    c = af * c + ai * ag;
    float hval = ao * tanhf_(c);
    if (!odd) {
      f16 hh = (f16)hval;
      ((f16*)&hbuf[p ^ 1][0])[j] = hh;
      hout[((long)b * TC + t) * Hh + j] = hh;
    }
    __syncthreads();
    p ^= 1;
    xc0 = xn0; xc1 = xn1;
    xptr0 = xn0p; xptr1 = xn1p;
  }
  if (!odd) c_state[b * Hh + j] = c;
  if (tid < 128) ((h2*)h_state)[b * 128 + tid] = hbuf[p][tid];
}

// ---------------- v512 scan (r9 exact, proven ~1440 us; chunk 1 control) ----
__global__ void __launch_bounds__(512, 2) lstm512_k(
    const f16* __restrict__ WhT2, const f16* __restrict__ xp,
    f16* __restrict__ hout, float* __restrict__ c_state, f16* __restrict__ h_state,
    int TC, int first)
{
  const int b = blockIdx.x, tid = threadIdx.x;
  const int j = tid >> 1, odd = tid & 1;
  __shared__ __align__(16) h2 hbuf[2][128];
  __shared__ uint4 wt[16][512];

  h2 w[192];
  {
    const uint4* p4 = (const uint4*)(WhT2 + (long)tid * 512);
#pragma unroll
    for (int u = 0; u < 48; ++u) {
      uint4 v = p4[u];
      w[4 * u + 0] = bch2(v.x); w[4 * u + 1] = bch2(v.y);
      w[4 * u + 2] = bch2(v.z); w[4 * u + 3] = bch2(v.w);
    }
#pragma unroll
    for (int gg = 0; gg < 16; ++gg) wt[gg][tid] = p4[48 + gg];
  }

  float c = first ? 0.f : c_state[b * Hh + j];
  if (tid < 128) {
    h2 hz = {(f16)0.f, (f16)0.f};
    hbuf[0][tid] = first ? hz : ((const h2*)h_state)[b * 128 + tid];
  }
  __syncthreads();

  const float sgn0 = odd ? 2.0f : -1.0f;
  const int xcol0 = (odd * 2) * 256 + j;
  const int xcol1 = xcol0 + 256;
  const f16* xbase = xp + (long)b * TC * G4;
  const f16* xptr0 = xbase + xcol0;
  const f16* xptr1 = xbase + xcol1;
  const f16* xend0 = xptr0 + (long)(TC - 1) * G4;
  f16 xc0 = *xptr0, xc1 = *xptr1;
  int p = 0;
  for (int t = 0; t < TC; ++t) {
    bool last = (xptr0 == xend0);
    const f16* xn0p = last ? xptr0 : xptr0 + G4;
    const f16* xn1p = last ? xptr1 : xptr1 + G4;
    f16 xn0 = *xn0p, xn1 = *xn1p;

    float a0 = (float)xc0, b0 = 0.f, a1 = (float)xc1, b1 = 0.f;
    const uint4* hb4 = (const uint4*)&hbuf[p][0];
#pragma unroll
    for (int i = 0; i < 24; ++i) {
      uint4 hv = hb4[i];
      a0 = fdot2f(w[4 * i + 0], bch2(hv.x), a0);
      b0 = fdot2f(w[4 * i + 1], bch2(hv.y), b0);
      a0 = fdot2f(w[4 * i + 2], bch2(hv.z), a0);
      b0 = fdot2f(w[4 * i + 3], bch2(hv.w), b0);
      a1 = fdot2f(w[96 + 4 * i + 0], bch2(hv.x), a1);
      b1 = fdot2f(w[96 + 4 * i + 1], bch2(hv.y), b1);
      a1 = fdot2f(w[96 + 4 * i + 2], bch2(hv.z), a1);
      b1 = fdot2f(w[96 + 4 * i + 3], bch2(hv.w), b1);
    }
#pragma unroll
    for (int gg = 0; gg < 8; ++gg) {
      uint4 hv = hb4[24 + gg];
      uint4 wa = wt[gg][tid];
      uint4 wb = wt[8 + gg][tid];
      a0 = fdot2f(bch2(wa.x), bch2(hv.x), a0);
      b0 = fdot2f(bch2(wa.y), bch2(hv.y), b0);
      a0 = fdot2f(bch2(wa.z), bch2(hv.z), a0);
      b0 = fdot2f(bch2(wa.w), bch2(hv.w), b0);
      a1 = fdot2f(bch2(wb.x), bch2(hv.x), a1);
      b1 = fdot2f(bch2(wb.y), bch2(hv.y), b1);
      a1 = fdot2f(bch2(wb.z), bch2(hv.z), a1);
      b1 = fdot2f(bch2(wb.w), bch2(hv.w), b1);
    }
    float A0 = a0 + b0, A1 = a1 + b1;

    float e0 = __expf(sgn0 * A0);
    float r0 = __builtin_amdgcn_rcpf(1.0f + e0);
    float act0 = odd ? 1.0f - 2.0f * r0 : r0;
    float e1 = __expf(-A1);
    float act1 = __builtin_amdgcn_rcpf(1.0f + e1);

    float px0 = qb<0xB1>(act0), px1 = qb<0xB1>(act1);
    float ai = odd ? px0 : act0;
    float af = odd ? px1 : act1;
    float ag = odd ? act0 : px0;
    float ao = odd ? act1 : px1;
    c = af * c + ai * ag;
    float hval = ao * tanhf_(c);
    if (!odd) {
      f16 hh = (f16)hval;
      ((f16*)&hbuf[p ^ 1][0])[j] = hh;
      hout[((long)b * TC + t) * Hh + j] = hh;
    }
    __syncthreads();
    p ^= 1;
    xc0 = xn0; xc1 = xn1;
    xptr0 = xn0p; xptr1 = xn1p;
  }
  if (!odd) c_state[b * Hh + j] = c;
  if (tid < 128) ((h2*)h_state)[b * 128 + tid] = hbuf[p][tid];
}

// ---------------- host ----------------
extern "C" void kernel_launch(void* const* d_in, const int* in_sizes, int n_in,
                              void* d_out, int out_size, void* d_ws, size_t ws_size,
                              hipStream_t stream)
{
  const float* x  = (const float*)d_in[0];
  const float* Wi = (const float*)d_in[1];
  const float* Wh = (const float*)d_in[2];
  const float* bh = (const float*)d_in[3];
  const float* W1 = (const float*)d_in[4];
  const float* b1 = (const float*)d_in[5];
  const float* W2 = (const float*)d_in[6];
  const float* b2 = (const float*)d_in[7];
  float* out = (float*)d_out;

  char* ws = (char*)d_ws;
  size_t off = 0;
  auto alloc = [&](size_t bytes) -> char* {
    char* p = ws + off;
    off = (off + bytes + 255) & ~(size_t)255;
    return p;
  };
  f16* x16   = (f16*)alloc((size_t)Bb * Tt * Xx * 2);
  f16* wi16  = (f16*)alloc((size_t)Xx * G4 * 2);
  f16* whT2  = (f16*)alloc((size_t)G4 * Hh * 2);
  f16* w116  = (f16*)alloc((size_t)Hh * Hh * 2);
  f16* w216  = (f16*)alloc((size_t)Hh * Z2 * 2);
  float* cst = (float*)alloc((size_t)Bb * Hh * 4);
  f16* hst   = (f16*)alloc((size_t)Bb * Hh * 2);

  int tc = 1024;  // 2 chunks: chunk0 = pk_fma experiment, chunk1 = control
  while (tc > 32) {
    size_t need = (size_t)Bb * tc * G4 * 2 + (size_t)Bb * tc * Hh * 2;
    if (off + need <= ws_size) break;
    tc >>= 1;
  }
  int tcsh = __builtin_ctz((unsigned)tc);
  f16* xp16 = (f16*)alloc((size_t)Bb * tc * G4 * 2);
  f16* h16  = (f16*)alloc((size_t)Bb * tc * Hh * 2);
  f16* hid16 = xp16;  // head hidden aliases xp (xp fully consumed by the scan)

  cast_f16_k<<<(Bb * Tt * Xx) / 1024, 256, 0, stream>>>(x, x16, Bb * Tt * Xx);
  cast_f16_k<<<(Xx * G4) / 1024, 256, 0, stream>>>(Wi, wi16, Xx * G4);
  cast_f16_k<<<(Hh * Hh) / 1024, 256, 0, stream>>>(W1, w116, Hh * Hh);
  cast_f16_k<<<(Hh * Z2) / 1024, 256, 0, stream>>>(W2, w216, Hh * Z2);
  cast_whT2_k<<<(Hh * G4) / 256, 256, 0, stream>>>(Wh, whT2);

  float* mu = out;
  float* ls = out + (size_t)Bb * Tt * 64;

  int ci = 0;
  for (int t0 = 0; t0 < Tt; t0 += tc, ++ci) {
    dim3 gx(Bb * tc / 64, G4 / 64);
    gemm_f16_k<<<gx, 256, 0, stream>>>(x16, wi16, bh, xp16, nullptr, nullptr,
                                       G4, Xx, tcsh, Tt, t0, 0, 0, 0);
    if (ci == 0)
      lstm512p_k<<<Bb, 512, 0, stream>>>(whT2, xp16, h16, cst, hst, tc, (t0 == 0) ? 1 : 0);
    else
      lstm512_k<<<Bb, 512, 0, stream>>>(whT2, xp16, h16, cst, hst, tc, (t0 == 0) ? 1 : 0);
    dim3 g1g(Bb * tc / 64, Hh / 64);
    gemm_f16_k<<<g1g, 256, 0, stream>>>(h16, w116, b1, hid16, nullptr, nullptr,
                                        Hh, Hh, 30, 0, 0, 1, 0, 0);
    dim3 g2g(Bb * tc / 64, Z2 / 64);
    gemm_f16_k<<<g2g, 256, 0, stream>>>(hid16, w216, b2, nullptr, mu, ls,
                                        Z2, Hh, 30, 0, 0, 2, t0, tcsh);
  }
}

// Round 13
// 3124.325 us; speedup vs baseline: 1.7092x; 1.0524x over previous
//
#include <hip/hip_runtime.h>

typedef _Float16 f16;
typedef _Float16 h2 __attribute__((ext_vector_type(2)));
typedef _Float16 h8 __attribute__((ext_vector_type(8)));
typedef float f4 __attribute__((ext_vector_type(4)));

constexpr int Bb = 64, Tt = 2048, Xx = 128, Hh = 256, G4 = 1024, Z2 = 128;

#if __has_attribute(amdgpu_num_vgpr)
#define NUM_VGPR256 __attribute__((amdgpu_num_vgpr(256)))
#else
#define NUM_VGPR256
#endif

__device__ __forceinline__ float fdot2f(h2 a, h2 b, float c) {
#if __has_builtin(__builtin_amdgcn_fdot2)
  return __builtin_amdgcn_fdot2(a, b, c, false);
#else
  return c + (float)a[0] * (float)b[0] + (float)a[1] * (float)b[1];
#endif
}
__device__ __forceinline__ float tanhf_(float x) {
  float e = __expf(2.0f * x);
  return 1.0f - 2.0f * __builtin_amdgcn_rcpf(e + 1.0f);
}
__device__ __forceinline__ h2 bch2(unsigned int u) { return __builtin_bit_cast(h2, u); }

template <int CTRL>
__device__ __forceinline__ float qb(float v) {  // quad_perm shuffle
  return __builtin_bit_cast(float,
      __builtin_amdgcn_mov_dpp(__builtin_bit_cast(int, v), CTRL, 0xf, 0xf, true));
}

// ---------------- casts ----------------
__global__ void cast_f16_k(const float* __restrict__ in, f16* __restrict__ out, int n) {
  int i = (blockIdx.x * 256 + threadIdx.x) * 4;
  if (i >= n) return;
  float4 v = *(const float4*)(in + i);
  h2 a = {(f16)v.x, (f16)v.y};
  h2 b = {(f16)v.z, (f16)v.w};
  uint2 o = {__builtin_bit_cast(unsigned int, a), __builtin_bit_cast(unsigned int, b)};
  *(uint2*)(out + i) = o;
}

// v512-layout: thread tid owns packed cols c0=2tid, c1=2tid+1 (cc -> gate cc&3,
// unit cc>>2; thread's gates: even tid (i,f) of unit tid>>1, odd tid (g,o)).
__global__ void cast_whT2_k(const float* __restrict__ Wh, f16* __restrict__ WhT2) {
  int idx = blockIdx.x * 256 + threadIdx.x;  // 262144 = 512 threads * 512 f16
  int tid = idx >> 9, f = idx & 511;
  int s = f >> 1, e = f & 1;
  int c_off, k;
  if (s < 96)      { c_off = 0; k = 2 * s + e; }
  else if (s < 192){ c_off = 1; k = 2 * (s - 96) + e; }
  else if (s < 224){ c_off = 0; k = 192 + 2 * (s - 192) + e; }
  else             { c_off = 1; k = 192 + 2 * (s - 224) + e; }
  int cc = 2 * tid + c_off;
  int j = cc >> 2, g = cc & 3;
  WhT2[(long)tid * 512 + f] = (f16)Wh[(long)k * G4 + g * 256 + j];
}

// ---------------- generic f16 MFMA GEMM, 64x64 tile ----------------
__global__ __launch_bounds__(256, 4) void gemm_f16_k(
    const f16* __restrict__ A, const f16* __restrict__ Bm, const float* __restrict__ bias,
    f16* __restrict__ C16, float* __restrict__ Cmu, float* __restrict__ Cls,
    int N, int K, int a_shift, int a_ostride, int a_t0,
    int mode, int o_t0, int tcshift)
{
  __shared__ __align__(16) f16 At[64][48];
  __shared__ __align__(16) f16 Bt[64][48];
  const int tid = threadIdx.x;
  const int mblk = blockIdx.x, nblk = blockIdx.y;
  const int w = tid >> 6, lane = tid & 63;

  const int sa_row = tid >> 2, sa_k = (tid & 3) * 8;
  const int m_g = mblk * 64 + sa_row;
  const long arow = (long)(m_g >> a_shift) * a_ostride + a_t0 + (m_g & ((1 << a_shift) - 1));
  const f16* aptr = A + arow * K + sa_k;
  const int sb_k = tid >> 3, sb_n = (tid & 7) * 8;
  const f16* bptr = Bm + (long)sb_k * N + nblk * 64 + sb_n;

  f4 acc[4];
#pragma unroll
  for (int i = 0; i < 4; ++i) acc[i] = (f4){0.f, 0.f, 0.f, 0.f};

  const int arow_l = w * 16 + (lane & 15);
  const int k0 = (lane >> 4) * 8;

  for (int kk = 0; kk < K; kk += 32) {
    uint4 av = *(const uint4*)(aptr + kk);
    uint4 bv = *(const uint4*)(bptr + (long)kk * N);
    __syncthreads();
    *(uint4*)&At[sa_row][sa_k] = av;
    h8 bx = __builtin_bit_cast(h8, bv);
#pragma unroll
    for (int j = 0; j < 8; ++j) Bt[sb_n + j][sb_k] = bx[j];
    __syncthreads();
    h8 af = *(const h8*)&At[arow_l][k0];
#pragma unroll
    for (int nt = 0; nt < 4; ++nt) {
      h8 bf = *(const h8*)&Bt[nt * 16 + (lane & 15)][k0];
      acc[nt] = __builtin_amdgcn_mfma_f32_16x16x32_f16(af, bf, acc[nt], 0, 0, 0);
    }
  }

  const int row_l = w * 16 + ((lane >> 4) << 2);
  const int col_l = lane & 15;
#pragma unroll
  for (int nt = 0; nt < 4; ++nt) {
    int gcol = nblk * 64 + nt * 16 + col_l;
    float bv = bias[gcol];
#pragma unroll
    for (int r = 0; r < 4; ++r) {
      int gm = mblk * 64 + row_l + r;
      float val = acc[nt][r] + bv;
      if (mode == 1) val = fmaxf(val, 0.f);
      if (mode <= 1) {
        C16[(long)gm * N + gcol] = (f16)val;
      } else {
        int bb = gm >> tcshift, tl = gm & ((1 << tcshift) - 1);
        long orow = (long)bb * Tt + o_t0 + tl;
        if (gcol < 64) Cmu[orow * 64 + gcol] = val;
        else Cls[orow * 64 + (gcol - 64)] = val;
      }
    }
  }
}

// Shared scan body for the v512 pair (identical math; kernel attrs differ).
#define LSTM512_BODY(WhT2, xp, hout, c_state, h_state, TC, first)              \
  const int b = blockIdx.x, tid = threadIdx.x;                                 \
  const int j = tid >> 1, odd = tid & 1;                                       \
  __shared__ __align__(16) h2 hbuf[2][128];                                    \
  __shared__ uint4 wt[16][512];                                                \
  h2 w[192];                                                                   \
  {                                                                            \
    const uint4* p4 = (const uint4*)(WhT2 + (long)tid * 512);                  \
    _Pragma("unroll") for (int u = 0; u < 48; ++u) {                           \
      uint4 v = p4[u];                                                         \
      w[4 * u + 0] = bch2(v.x); w[4 * u + 1] = bch2(v.y);                      \
      w[4 * u + 2] = bch2(v.z); w[4 * u + 3] = bch2(v.w);                      \
    }                                                                          \
    _Pragma("unroll") for (int gg = 0; gg < 16; ++gg) wt[gg][tid] = p4[48 + gg]; \
  }                                                                            \
  float c = first ? 0.f : c_state[b * Hh + j];                                 \
  if (tid < 128) {                                                             \
    h2 hz = {(f16)0.f, (f16)0.f};                                              \
    hbuf[0][tid] = first ? hz : ((const h2*)h_state)[b * 128 + tid];           \
  }                                                                            \
  __syncthreads();                                                             \
  const float sgn0 = odd ? 2.0f : -1.0f;                                       \
  const int xcol0 = (odd * 2) * 256 + j;                                       \
  const int xcol1 = xcol0 + 256;                                               \
  const f16* xbase = xp + (long)b * TC * G4;                                   \
  const f16* xptr0 = xbase + xcol0;                                            \
  const f16* xptr1 = xbase + xcol1;                                            \
  const f16* xend0 = xptr0 + (long)(TC - 1) * G4;                              \
  f16 xc0 = *xptr0, xc1 = *xptr1;                                              \
  int p = 0;                                                                   \
  for (int t = 0; t < TC; ++t) {                                               \
    bool last = (xptr0 == xend0);                                              \
    const f16* xn0p = last ? xptr0 : xptr0 + G4;                               \
    const f16* xn1p = last ? xptr1 : xptr1 + G4;                               \
    f16 xn0 = *xn0p, xn1 = *xn1p;                                              \
    float a0 = (float)xc0, b0 = 0.f, a1 = (float)xc1, b1 = 0.f;                \
    const uint4* hb4 = (const uint4*)&hbuf[p][0];                              \
    _Pragma("unroll") for (int i = 0; i < 24; ++i) {                           \
      uint4 hv = hb4[i];                                                       \
      a0 = fdot2f(w[4 * i + 0], bch2(hv.x), a0);                               \
      b0 = fdot2f(w[4 * i + 1], bch2(hv.y), b0);                               \
      a0 = fdot2f(w[4 * i + 2], bch2(hv.z), a0);                               \
      b0 = fdot2f(w[4 * i + 3], bch2(hv.w), b0);                               \
      a1 = fdot2f(w[96 + 4 * i + 0], bch2(hv.x), a1);                          \
      b1 = fdot2f(w[96 + 4 * i + 1], bch2(hv.y), b1);                          \
      a1 = fdot2f(w[96 + 4 * i + 2], bch2(hv.z), a1);                          \
      b1 = fdot2f(w[96 + 4 * i + 3], bch2(hv.w), b1);                          \
    }                                                                          \
    _Pragma("unroll") for (int gg = 0; gg < 8; ++gg) {                         \
      uint4 hv = hb4[24 + gg];                                                 \
      uint4 wa = wt[gg][tid];                                                  \
      uint4 wb = wt[8 + gg][tid];                                              \
      a0 = fdot2f(bch2(wa.x), bch2(hv.x), a0);                                 \
      b0 = fdot2f(bch2(wa.y), bch2(hv.y), b0);                                 \
      a0 = fdot2f(bch2(wa.z), bch2(hv.z), a0);                                 \
      b0 = fdot2f(bch2(wa.w), bch2(hv.w), b0);                                 \
      a1 = fdot2f(bch2(wb.x), bch2(hv.x), a1);                                 \
      b1 = fdot2f(bch2(wb.y), bch2(hv.y), b1);                                 \
      a1 = fdot2f(bch2(wb.z), bch2(hv.z), a1);                                 \
      b1 = fdot2f(bch2(wb.w), bch2(hv.w), b1);                                 \
    }                                                                          \
    float A0 = a0 + b0, A1 = a1 + b1;                                          \
    float e0 = __expf(sgn0 * A0);                                              \
    float r0 = __builtin_amdgcn_rcpf(1.0f + e0);                               \
    float act0 = odd ? 1.0f - 2.0f * r0 : r0;                                  \
    float e1 = __expf(-A1);                                                    \
    float act1 = __builtin_amdgcn_rcpf(1.0f + e1);                             \
    float px0 = qb<0xB1>(act0), px1 = qb<0xB1>(act1);                          \
    float ai = odd ? px0 : act0;                                               \
    float af = odd ? px1 : act1;                                               \
    float ag = odd ? act0 : px0;                                               \
    float ao = odd ? act1 : px1;                                               \
    c = af * c + ai * ag;                                                      \
    float hval = ao * tanhf_(c);                                               \
    if (!odd) {                                                                \
      f16 hh = (f16)hval;                                                      \
      ((f16*)&hbuf[p ^ 1][0])[j] = hh;                                         \
      hout[((long)b * TC + t) * Hh + j] = hh;                                  \
    }                                                                          \
    __syncthreads();                                                           \
    p ^= 1;                                                                    \
    xc0 = xn0; xc1 = xn1;                                                      \
    xptr0 = xn0p; xptr1 = xn1p;                                                \
  }                                                                            \
  if (!odd) c_state[b * Hh + j] = c;                                           \
  if (tid < 128) ((h2*)h_state)[b * 128 + tid] = hbuf[p][tid];

// ---------------- v512v: explicit 256-VGPR request (chunk 0, experiment) ----
// Every indirect occupancy directive (waves_per_eu, flat_work_group_size,
// launch_bounds min-waves) left the arch allocation pinned at 128, parking
// ~半 the weights in AGPRs (1 v_accvgpr_read per use ~ 500 cyc/step/SIMD).
// amdgpu_num_vgpr(256) is the DIRECT allocation request: w[192]+working=~237
// fits entirely in arch regs -> tax eliminated.
__global__ void __launch_bounds__(512) NUM_VGPR256 lstm512v_k(
    const f16* __restrict__ WhT2, const f16* __restrict__ xp,
    f16* __restrict__ hout, float* __restrict__ c_state, f16* __restrict__ h_state,
    int TC, int first)
{
  LSTM512_BODY(WhT2, xp, hout, c_state, h_state, TC, first)
}

// ---------------- v512 (r9 exact, proven ~1440 us; chunk 1 control) ---------
__global__ void __launch_bounds__(512, 2) lstm512_k(
    const f16* __restrict__ WhT2, const f16* __restrict__ xp,
    f16* __restrict__ hout, float* __restrict__ c_state, f16* __restrict__ h_state,
    int TC, int first)
{
  LSTM512_BODY(WhT2, xp, hout, c_state, h_state, TC, first)
}

// ---------------- host ----------------
extern "C" void kernel_launch(void* const* d_in, const int* in_sizes, int n_in,
                              void* d_out, int out_size, void* d_ws, size_t ws_size,
                              hipStream_t stream)
{
  const float* x  = (const float*)d_in[0];
  const float* Wi = (const float*)d_in[1];
  const float* Wh = (const float*)d_in[2];
  const float* bh = (const float*)d_in[3];
  const float* W1 = (const float*)d_in[4];
  const float* b1 = (const float*)d_in[5];
  const float* W2 = (const float*)d_in[6];
  const float* b2 = (const float*)d_in[7];
  float* out = (float*)d_out;

  char* ws = (char*)d_ws;
  size_t off = 0;
  auto alloc = [&](size_t bytes) -> char* {
    char* p = ws + off;
    off = (off + bytes + 255) & ~(size_t)255;
    return p;
  };
  f16* x16   = (f16*)alloc((size_t)Bb * Tt * Xx * 2);
  f16* wi16  = (f16*)alloc((size_t)Xx * G4 * 2);
  f16* whT2  = (f16*)alloc((size_t)G4 * Hh * 2);
  f16* w116  = (f16*)alloc((size_t)Hh * Hh * 2);
  f16* w216  = (f16*)alloc((size_t)Hh * Z2 * 2);
  float* cst = (float*)alloc((size_t)Bb * Hh * 4);
  f16* hst   = (f16*)alloc((size_t)Bb * Hh * 2);

  int tc = 1024;  // 2 chunks: chunk0 = num_vgpr(256) experiment, chunk1 = control
  while (tc > 32) {
    size_t need = (size_t)Bb * tc * G4 * 2 + (size_t)Bb * tc * Hh * 2;
    if (off + need <= ws_size) break;
    tc >>= 1;
  }
  int tcsh = __builtin_ctz((unsigned)tc);
  f16* xp16 = (f16*)alloc((size_t)Bb * tc * G4 * 2);
  f16* h16  = (f16*)alloc((size_t)Bb * tc * Hh * 2);
  f16* hid16 = xp16;  // head hidden aliases xp (xp fully consumed by the scan)

  cast_f16_k<<<(Bb * Tt * Xx) / 1024, 256, 0, stream>>>(x, x16, Bb * Tt * Xx);
  cast_f16_k<<<(Xx * G4) / 1024, 256, 0, stream>>>(Wi, wi16, Xx * G4);
  cast_f16_k<<<(Hh * Hh) / 1024, 256, 0, stream>>>(W1, w116, Hh * Hh);
  cast_f16_k<<<(Hh * Z2) / 1024, 256, 0, stream>>>(W2, w216, Hh * Z2);
  cast_whT2_k<<<(Hh * G4) / 256, 256, 0, stream>>>(Wh, whT2);

  float* mu = out;
  float* ls = out + (size_t)Bb * Tt * 64;

  int ci = 0;
  for (int t0 = 0; t0 < Tt; t0 += tc, ++ci) {
    dim3 gx(Bb * tc / 64, G4 / 64);
    gemm_f16_k<<<gx, 256, 0, stream>>>(x16, wi16, bh, xp16, nullptr, nullptr,
                                       G4, Xx, tcsh, Tt, t0, 0, 0, 0);
    if (ci == 0)
      lstm512v_k<<<Bb, 512, 0, stream>>>(whT2, xp16, h16, cst, hst, tc, (t0 == 0) ? 1 : 0);
    else
      lstm512_k<<<Bb, 512, 0, stream>>>(whT2, xp16, h16, cst, hst, tc, (t0 == 0) ? 1 : 0);
    dim3 g1g(Bb * tc / 64, Hh / 64);
    gemm_f16_k<<<g1g, 256, 0, stream>>>(h16, w116, b1, hid16, nullptr, nullptr,
                                        Hh, Hh, 30, 0, 0, 1, 0, 0);
    dim3 g2g(Bb * tc / 64, Z2 / 64);
    gemm_f16_k<<<g2g, 256, 0, stream>>>(hid16, w216, b2, nullptr, mu, ls,
                                        Z2, Hh, 30, 0, 0, 2, t0, tcsh);
  }
}